// Round 18
// baseline (668.189 us; speedup 1.0000x reference)
//
#include <hip/hip_runtime.h>

// Shapes (fixed): B=4, N=256, F=6, H=128, D=256, B*N=1024
// All tensors fp32. out = concat(adj_pred [4,256,256], feat_pred [4,256,6]).
// Single persistent kernel, 768 blocks x 256 threads (3/CU co-resident),
// grid barrier v3: s_sleep-paced polling, replicated gen lines, 2-level arrival.
// Stage bodies are the round-17 proven kernels.

typedef float v4f __attribute__((ext_vector_type(4)));
typedef short v8s __attribute__((ext_vector_type(8)));

#define NBLK 768

__device__ __forceinline__ unsigned short f2bs(float f) {
    union { float f; unsigned int u; } v;
    v.f = f;
    return (unsigned short)((v.u + 0x7fffu + ((v.u >> 16) & 1u)) >> 16);
}

// ---- grid barrier v3 ----
// ctrl ints: pcnt[p] at p*32 (p<16), mcnt at 512, gen[r] at 576+r*32 (r<8)
__device__ void gbar(int* ctrl) {
    __syncthreads();
    if (threadIdx.x == 0) {
        volatile int* genp = (volatile int*)(ctrl + 576 + (blockIdx.x & 7) * 32);
        int g = *genp;
        __threadfence();
        int p = blockIdx.x & 15;
        const int per = NBLK / 16;                    // 48
        if (atomicAdd(ctrl + p * 32, 1) == per - 1) {
            if (atomicAdd(ctrl + 512, per) == NBLK - per) {
                for (int q = 0; q < 16; q++) atomicExch(ctrl + q * 32, 0);
                atomicExch(ctrl + 512, 0);
                __threadfence();
                for (int q = 0; q < 8; q++) atomicAdd(ctrl + 576 + q * 32, 1);
            }
        }
        long it = 0;
        while (*genp == g) {
            __builtin_amdgcn_s_sleep(16);             // ~1024 cyc between polls
            if (++it > 2000000L) break;               // hedge: never hard-hang
        }
    }
    __syncthreads();
    __threadfence();
}

// ---- tiled GEMM, 16x32 tile, chunked K staging (R11/R17-proven) ----
__device__ void dev_tile(int t, const float* A, const float* B, const float* bias,
                         const float* dgA, float* anOut,
                         const float* stat, const float* g, const float* beta,
                         float* ostat, float* C,
                         int K, int N, int relu,
                         int sA, int sB, int sC, int tiles_n, int tiles_m,
                         float* smem) {
    float* As = smem;           // [16][17] = 272
    float* Bs = smem + 272;     // [16][33] = 528
    int tid = threadIdx.x;
    int n2 = tid & 15, ml = tid >> 4;
    int bx = t % tiles_n;
    int tmp = t / tiles_n;
    int by = tmp % tiles_m;
    int bz = tmp / tiles_m;
    int m0 = by * 16, n0 = bx * 32;
    const float* Ab = A + (long)bz * sA;
    const float* Bb = B + (long)bz * sB;
    float* Cb = C + (long)bz * sC;
    const float* dgb = (dgA != 0) ? (dgA + bz * 256) : 0;
    int kk = tid & 15, mm = tid >> 4;
    float di = (dgA != 0) ? dgb[m0 + mm] : 0.f;
    float c0 = 0.f, c1 = 0.f;
    for (int k0 = 0; k0 < K; k0 += 16) {
        int kg = k0 + kk;
        float v = Ab[(long)(m0 + mm) * K + kg];
        if (dgA != 0) {
            if (m0 + mm == kg) v += 1.f;
            v = di * v * dgb[kg];
            if (anOut != 0 && bx == 0)
                anOut[bz * 65536 + (m0 + mm) * 256 + kg] = v;
        } else if (stat != 0) {
            float mu = stat[kg] * (1.f / 1024.f);
            float vr = stat[128 + kg] * (1.f / 1024.f) - mu * mu;
            float sc = rsqrtf(vr + 1e-5f) * g[kg];
            v = (v - mu) * sc + beta[kg];
            if (v < 0.f) v = 0.f;
        }
        As[kk * 17 + mm] = v;
        int nn2 = tid & 31, kk2 = tid >> 5;
        Bs[kk2 * 33 + nn2] = Bb[(long)(k0 + kk2) * N + n0 + nn2];
        int idx = tid + 256;
        nn2 = idx & 31; kk2 = idx >> 5;
        Bs[kk2 * 33 + nn2] = Bb[(long)(k0 + kk2) * N + n0 + nn2];
        __syncthreads();
        #pragma unroll
        for (int q = 0; q < 16; q++) {
            float a = As[q * 17 + ml];
            c0 += a * Bs[q * 33 + n2 * 2];
            c1 += a * Bs[q * 33 + n2 * 2 + 1];
        }
        __syncthreads();
    }
    int mRow = m0 + ml, nn = n0 + n2 * 2;
    if (bias != 0) { c0 += bias[nn]; c1 += bias[nn + 1]; }
    if (relu) {
        if (c0 < 0.f) c0 = 0.f;
        if (c1 < 0.f) c1 = 0.f;
    }
    Cb[(long)mRow * N + nn] = c0;
    Cb[(long)mRow * N + nn + 1] = c1;

    if (ostat != 0) {
        float* sred = smem + 800;
        float* qred = smem + 1344;
        __syncthreads();
        sred[(n2 * 2) * 17 + ml] = c0;
        sred[(n2 * 2 + 1) * 17 + ml] = c1;
        qred[(n2 * 2) * 17 + ml] = c0 * c0;
        qred[(n2 * 2 + 1) * 17 + ml] = c1 * c1;
        __syncthreads();
        if (tid < 32) {
            float s = 0.f, q = 0.f;
            for (int u = 0; u < 16; u++) {
                s += sred[tid * 17 + u];
                q += qred[tid * 17 + u];
            }
            atomicAdd(&ostat[n0 + tid], s);
            atomicAdd(&ostat[128 + n0 + tid], q);
        }
    }
}

__global__ void k_all(const float* x, const float* adj,
                      const float* W1, const float* b1,
                      const float* W2, const float* b2,
                      const float* W3, const float* b3,
                      const float* g1, const float* be1,
                      const float* g2, const float* be2,
                      const float* e1w, const float* e1b,
                      const float* e2w, const float* e2b,
                      const float* e3w, const float* e3b,
                      const float* f1w, const float* f1b,
                      const float* f2w, const float* f2b_,
                      const float* f3w, const float* f3b,
                      float* ws, float* out) {
    __shared__ float smem[4608];                 // 18.4 KB (max over stages)

    int* ctrl = (int*)ws;                        // ints [0,1024)
    float* st1 = ws + 1024;                      // 256
    float* st2 = ws + 1280;                      // 256
    float* dg  = ws + 1536;                      // 1024
    unsigned short* bfr_g = (unsigned short*)(ws + 2560);  // 8192 ushorts
    float* An  = ws + 6656;                      // 262144
    float* buf = An + 262144;
    float* hb  = buf + 262144;
    float* lg  = hb + 262144;
    float* h1  = lg + 262144;                    // 131072 (later f1)
    float* h2  = h1 + 131072;
    float* hi  = h2 + 131072;
    float* hj  = hi + 131072;                    // contiguous after hi

    int tid = threadIdx.x;
    int blk = blockIdx.x;

    // ---- S0: x@W1 + degree + e2w swizzle + zero BN accumulators ----
    if (blk < 512) {
        int idx = blk * 256 + tid;
        int m = idx >> 7, n = idx & 127;
        float s = 0.f;
        for (int k = 0; k < 6; k++) s += x[m * 6 + k] * W1[k * 128 + n];
        buf[idx] = s;
        if (blk < 32) {
            int s2 = blk * 256 + tid;            // 8192 e2w entries
            int k = s2 >> 6, n2 = s2 & 63;
            int kc = k >> 5, q = (k & 31) >> 3, t = k & 7;
            int nt = n2 >> 4, c2 = n2 & 15;
            bfr_g[(((nt * 4 + kc) * 64) + q * 16 + c2) * 8 + t] = f2bs(e2w[s2]);
        } else if (blk == 32) {
            st1[tid] = 0.f;                      // st1+st2 contiguous 512
            st1[256 + tid] = 0.f;
        }
    } else {
        float* ss = smem;
        int row = (blk - 512) * 4 + (tid >> 6);
        int lane = tid & 63;
        const float* ap = adj + (long)row * 256;
        ss[tid] = ap[lane] + ap[lane + 64] + ap[lane + 128] + ap[lane + 192];
        __syncthreads();
        for (int o = 32; o > 0; o >>= 1) {
            if (lane < o) ss[tid] += ss[tid + o];
            __syncthreads();
        }
        if (lane == 0) {
            float t = ss[tid] + 1.f;
            if (t < 1.f) t = 1.f;
            dg[row] = rsqrtf(t);
        }
    }
    gbar(ctrl);

    // ---- S1: h1 = norm(adj)@buf + b1 (+stats->st1); An materialized ----
    if (blk < 256)
        dev_tile(blk, adj, buf, b1, dg, An, 0, 0, 0, st1, h1,
                 256, 128, 0, 65536, 32768, 32768, 4, 16, smem);
    gbar(ctrl);

    // ---- S2: buf = BN(h1)@W2 ----
    if (blk < 256)
        dev_tile(blk, h1, W2, 0, 0, 0, st1, g1, be1, 0, buf,
                 128, 128, 0, 0, 0, 0, 4, 64, smem);
    gbar(ctrl);

    // ---- S3: h2 = An@buf + b2 (+stats->st2) ----
    if (blk < 256)
        dev_tile(blk, An, buf, b2, 0, 0, 0, 0, 0, st2, h2,
                 256, 128, 0, 65536, 32768, 32768, 4, 16, smem);
    gbar(ctrl);

    // ---- S4: buf = BN(h2)@W3 ----
    if (blk < 512)
        dev_tile(blk, h2, W3, 0, 0, 0, st2, g2, be2, 0, buf,
                 128, 256, 0, 0, 0, 0, 8, 64, smem);
    gbar(ctrl);

    // ---- S5: hb = relu(An@buf + b3) ----
    if (blk < 512)
        dev_tile(blk, An, buf, b3, 0, 0, 0, 0, 0, 0, hb,
                 256, 256, 1, 65536, 65536, 65536, 8, 16, smem);
    gbar(ctrl);

    // ---- S6: hi/hj = hb@e1w (batch-2) + f1 = relu(hb@f1w+f1b) ----
    if (blk < 512)
        dev_tile(blk, hb, e1w, 0, 0, 0, 0, 0, 0, 0, hi,
                 256, 128, 0, 0, 32768, 131072, 4, 64, smem);
    else
        dev_tile(blk - 512, hb, f1w, f1b, 0, 0, 0, 0, 0, 0, h1,
                 256, 128, 1, 0, 0, 0, 4, 64, smem);
    gbar(ctrl);

    // ---- S7: MFMA pair decoder (units 0..1023) + feature f2/f3 (1024..1279) ----
    for (int u = blk; u < 1280; u += NBLK) {
        __syncthreads();
        if (u < 1024) {
            float* red = smem;                       // [256][17] = 4352
            float* pre_sh = smem + 4352;             // 128
            int lane = tid & 63, wv = tid >> 6;
            int col = lane & 15, quad = lane >> 4;
            int bi = u, b = bi >> 8;
            if (tid < 128) pre_sh[tid] = hi[bi * 128 + tid] + e1b[tid];
            __syncthreads();
            float e2bv[4], e3wv[4];
            for (int nt = 0; nt < 4; nt++) {
                e2bv[nt] = e2b[nt * 16 + col];
                e3wv[nt] = e3w[nt * 16 + col];
            }
            const float* hjb = hj + b * 32768;
            #pragma unroll 1
            for (int ms = 0; ms < 4; ms++) {
                v4f acc[4];
                for (int nt = 0; nt < 4; nt++) {
                    v4f z = {0.f, 0.f, 0.f, 0.f};
                    acc[nt] = z;
                }
                int j = wv * 64 + ms * 16 + col;
                const float* rowp = hjb + j * 128 + quad * 8;
                #pragma unroll 1
                for (int kc = 0; kc < 4; kc++) {
                    const float* pp = pre_sh + kc * 32 + quad * 8;
                    const float* hp = rowp + kc * 32;
                    v8s af;
                    #pragma unroll
                    for (int t = 0; t < 8; t++) {
                        float p = pp[t] + hp[t];
                        p = (p > 0.f) ? p : 0.f;
                        af[t] = (short)f2bs(p);
                    }
                    #pragma unroll
                    for (int nt = 0; nt < 4; nt++) {
                        v8s bf = *(const v8s*)&bfr_g[(((nt * 4 + kc) * 64) + lane) * 8];
                        acc[nt] = __builtin_amdgcn_mfma_f32_16x16x32_bf16(
                            af, bf, acc[nt], 0, 0, 0);
                    }
                }
                #pragma unroll
                for (int r = 0; r < 4; r++) {
                    float s = 0.f;
                    #pragma unroll
                    for (int nt = 0; nt < 4; nt++) {
                        float v = acc[nt][r] + e2bv[nt];
                        if (v > 0.f) s += v * e3wv[nt];
                    }
                    red[(wv * 64 + ms * 16 + quad * 4 + r) * 17 + col] = s;
                }
            }
            __syncthreads();
            float s = e3b[0];
            for (int c = 0; c < 16; c++) s += red[tid * 17 + c];
            lg[bi * 256 + tid] = s;
        } else {
            float* f2row = smem;                     // 512 floats
            int r0 = (u - 1024) * 4;
            for (int p = 0; p < 2; p++) {
                int idx = tid + p * 256;
                int r = r0 + (idx >> 7), n = idx & 127;
                float s = f2b_[n];
                const float* f1r = h1 + (long)r * 128;
                for (int k = 0; k < 128; k++) s += f1r[k] * f2w[k * 128 + n];
                if (s < 0.f) s = 0.f;
                f2row[idx] = s;
            }
            __syncthreads();
            if (tid < 24) {
                int r = tid / 6, c = tid % 6;
                float s = f3b[c];
                const float* fr = f2row + r * 128;
                for (int k = 0; k < 128; k++) s += fr[k] * f3w[k * 6 + c];
                out[262144 + (r0 + r) * 6 + c] = s;
            }
        }
    }
    gbar(ctrl);

    // ---- S8: tiled symmetrize + sigmoid (144 tile-pairs) ----
    if (blk < 144) {
        float* Ta = smem;                            // 32*33
        float* Tb = smem + 1056;                     // 32*33
        int b = blk / 36;
        int t = blk % 36;
        int ti = 0, rem = t;
        while (rem >= 8 - ti) { rem -= 8 - ti; ti++; }
        int tj = ti + rem;
        int i0 = ti * 32, j0 = tj * 32;
        const float* lgb = lg + b * 65536;
        for (int p = 0; p < 4; p++) {
            int idx = p * 256 + tid;
            int r = idx >> 5, c = idx & 31;
            Ta[r * 33 + c] = lgb[(i0 + r) * 256 + j0 + c];
            Tb[r * 33 + c] = lgb[(j0 + r) * 256 + i0 + c];
        }
        __syncthreads();
        float* ob = out + b * 65536;
        for (int p = 0; p < 4; p++) {
            int idx = p * 256 + tid;
            int r = idx >> 5, c = idx & 31;
            float v1 = 0.5f * (Ta[r * 33 + c] + Tb[c * 33 + r]);
            ob[(i0 + r) * 256 + j0 + c] = 1.f / (1.f + expf(-v1));
            float v2 = 0.5f * (Tb[r * 33 + c] + Ta[c * 33 + r]);
            ob[(j0 + r) * 256 + i0 + c] = 1.f / (1.f + expf(-v2));
        }
    }
}

extern "C" void kernel_launch(void* const* d_in, const int* in_sizes, int n_in,
                              void* d_out, int out_size, void* d_ws, size_t ws_size,
                              hipStream_t stream) {
    if (ws_size < (size_t)1600000 * 4) {
        hipMemsetAsync(d_out, 0x60, 4096, stream);   // diagnostic
        return;
    }
    // zero barrier control (ints [0,1024))
    hipMemsetAsync(d_ws, 0, 4096, stream);

    k_all<<<NBLK, 256, 0, stream>>>(
        (const float*)d_in[0],  (const float*)d_in[1],
        (const float*)d_in[2],  (const float*)d_in[3],
        (const float*)d_in[4],  (const float*)d_in[5],
        (const float*)d_in[6],  (const float*)d_in[7],
        (const float*)d_in[8],  (const float*)d_in[9],
        (const float*)d_in[10], (const float*)d_in[11],
        (const float*)d_in[12], (const float*)d_in[13],
        (const float*)d_in[14], (const float*)d_in[15],
        (const float*)d_in[16], (const float*)d_in[17],
        (const float*)d_in[18], (const float*)d_in[19],
        (const float*)d_in[20], (const float*)d_in[21],
        (const float*)d_in[22], (const float*)d_in[23],
        (float*)d_ws, (float*)d_out);
}

// Round 19
// 213.754 us; speedup vs baseline: 3.1260x; 3.1260x over previous
//
#include <hip/hip_runtime.h>

// Shapes (fixed): B=4, N=256, F=6, H=128, D=256, B*N=1024
// All tensors fp32. out = concat(adj_pred [4,256,256], feat_pred [4,256,6]).
// 9 launches (R15 structure, measured best). Vectorized-LDS GEMM inner loop.

typedef float v4f __attribute__((ext_vector_type(4)));
typedef short v8s __attribute__((ext_vector_type(8)));

__device__ __forceinline__ unsigned short f2bs(float f) {
    union { float f; unsigned int u; } v;
    v.f = f;
    return (unsigned short)((v.u + 0x7fffu + ((v.u >> 16) & 1u)) >> 16);
}

// ---- L0: role-split prologue ----
__global__ void k_pre(const float* x, const float* W1, const float* adj,
                      const float* e2w, float* buf, float* dg,
                      unsigned short* bfr_g, float* st) {
    __shared__ float ss[256];
    int blk = blockIdx.x, tid = threadIdx.x;
    if (blk < 512) {
        int idx = blk * 256 + tid;
        int m = idx >> 7, n = idx & 127;
        float s = 0.f;
        for (int k = 0; k < 6; k++) s += x[m * 6 + k] * W1[k * 128 + n];
        buf[idx] = s;
    } else if (blk < 768) {
        int row = (blk - 512) * 4 + (tid >> 6);
        int lane = tid & 63;
        const float* ap = adj + (long)row * 256;
        ss[tid] = ap[lane] + ap[lane + 64] + ap[lane + 128] + ap[lane + 192];
        __syncthreads();
        for (int o = 32; o > 0; o >>= 1) {
            if (lane < o) ss[tid] += ss[tid + o];
            __syncthreads();
        }
        if (lane == 0) {
            float t = ss[tid] + 1.f;
            if (t < 1.f) t = 1.f;
            dg[row] = rsqrtf(t);
        }
    } else {
        for (int s = tid; s < 8192; s += 256) {
            int k = s >> 6, n = s & 63;
            int kc = k >> 5, q = (k & 31) >> 3, t = k & 7;
            int nt = n >> 4, c2 = n & 15;
            bfr_g[(((nt * 4 + kc) * 64) + q * 16 + c2) * 8 + t] = f2bs(e2w[s]);
        }
        st[tid] = 0.f;
        st[256 + tid] = 0.f;
    }
}

// ---- tiled GEMM, 16x32 tile, one-shot full-K staging, vector LDS reads ----
//  A-tile stored [16][K+4] (q contiguous) -> b128 broadcast reads.
//  dgA: fold diag(dg)(A+I)diag(dg); anOut: materialize folded A (bx==0)
//  stat: consumer-BN affine; ostat: column sum/sumsq via atomics
__device__ void dev_tile(int t, const float* A, const float* B, const float* bias,
                         const float* dgA, float* anOut,
                         const float* stat, const float* g, const float* beta,
                         float* ostat, float* C,
                         int K, int N, int relu,
                         int sA, int sB, int sC, int tiles_n, int tiles_m,
                         float* smem) {
    int strideA = K + 4;              // 260 or 132 (x4B, 16B-aligned rows)
    float* As = smem;                 // [16][K+4]  <= 4160
    float* Bs = smem + 4160;          // [K][32]    <= 8192
    int tid = threadIdx.x;
    int n2 = tid & 15, ml = tid >> 4;
    int bx = t % tiles_n;
    int tmp = t / tiles_n;
    int by = tmp % tiles_m;
    int bz = tmp / tiles_m;
    int m0 = by * 16, n0 = bx * 32;
    const float* Ab = A + (long)bz * sA;
    const float* Bb = B + (long)bz * sB;
    float* Cb = C + (long)bz * sC;
    const float* dgb = (dgA != 0) ? (dgA + bz * 256) : 0;

    int kk = tid & 15, mm = tid >> 4;
    int nb = tid & 31, kb = tid >> 5;
    float di = (dgA != 0) ? dgb[m0 + mm] : 0.f;
    for (int ka = 0; ka < K; ka += 16) {
        int kg = ka + kk;
        float v = Ab[(long)(m0 + mm) * K + kg];
        if (dgA != 0) {
            if (m0 + mm == kg) v += 1.f;
            v = di * v * dgb[kg];
            if (anOut != 0 && bx == 0)
                anOut[bz * 65536 + (m0 + mm) * 256 + kg] = v;
        } else if (stat != 0) {
            float mu = stat[kg] * (1.f / 1024.f);
            float vr = stat[128 + kg] * (1.f / 1024.f) - mu * mu;
            float sc = rsqrtf(vr + 1e-5f) * g[kg];
            v = (v - mu) * sc + beta[kg];
            if (v < 0.f) v = 0.f;
        }
        As[mm * strideA + kg] = v;
        int kg2 = ka + kb;
        Bs[kg2 * 32 + nb] = Bb[(long)kg2 * N + n0 + nb];
        kg2 = ka + kb + 8;
        Bs[kg2 * 32 + nb] = Bb[(long)kg2 * N + n0 + nb];
    }
    __syncthreads();
    float c0 = 0.f, c1 = 0.f;
    const float* arow = As + ml * strideA;
    const float* bcol = Bs + n2 * 2;
    #pragma unroll 2
    for (int q0 = 0; q0 < K; q0 += 4) {
        float4 av = *(const float4*)(arow + q0);
        float2 b0 = *(const float2*)(bcol + (q0 + 0) * 32);
        float2 b1 = *(const float2*)(bcol + (q0 + 1) * 32);
        float2 b2 = *(const float2*)(bcol + (q0 + 2) * 32);
        float2 b3 = *(const float2*)(bcol + (q0 + 3) * 32);
        c0 += av.x * b0.x; c1 += av.x * b0.y;
        c0 += av.y * b1.x; c1 += av.y * b1.y;
        c0 += av.z * b2.x; c1 += av.z * b2.y;
        c0 += av.w * b3.x; c1 += av.w * b3.y;
    }
    int mRow = m0 + ml, nn = n0 + n2 * 2;
    if (bias != 0) { c0 += bias[nn]; c1 += bias[nn + 1]; }
    if (relu) {
        if (c0 < 0.f) c0 = 0.f;
        if (c1 < 0.f) c1 = 0.f;
    }
    Cb[(long)mRow * N + nn] = c0;
    Cb[(long)mRow * N + nn + 1] = c1;

    if (ostat != 0) {
        float* sred = smem;
        float* qred = smem + 544;
        __syncthreads();
        sred[(n2 * 2) * 17 + ml] = c0;
        sred[(n2 * 2 + 1) * 17 + ml] = c1;
        qred[(n2 * 2) * 17 + ml] = c0 * c0;
        qred[(n2 * 2 + 1) * 17 + ml] = c1 * c1;
        __syncthreads();
        if (tid < 32) {
            float s = 0.f, q = 0.f;
            for (int u = 0; u < 16; u++) {
                s += sred[tid * 17 + u];
                q += qred[tid * 17 + u];
            }
            atomicAdd(&ostat[n0 + tid], s);
            atomicAdd(&ostat[128 + n0 + tid], q);
        }
    }
}

__global__ void k_tgemm(const float* A, const float* B, const float* bias,
                        const float* dgA, float* anOut,
                        const float* stat, const float* g, const float* beta,
                        float* ostat, float* C,
                        int K, int N, int relu,
                        int sA, int sB, int sC, int tiles_n, int tiles_m) {
    __shared__ float smem[12352];
    dev_tile(blockIdx.x, A, B, bias, dgA, anOut, stat, g, beta, ostat, C,
             K, N, relu, sA, sB, sC, tiles_n, tiles_m, smem);
}

// ---- L7: {hi|hj = hb@e1w (batch-2)} + {f1 = relu(hb@f1w+f1b)} ----
__global__ void k_g67(const float* hb, const float* e1w, float* hi,
                      const float* f1w, const float* f1b, float* f1) {
    __shared__ float smem[12352];
    int t = blockIdx.x;
    if (t < 512) {
        dev_tile(t, hb, e1w, 0, 0, 0, 0, 0, 0, 0, hi,
                 256, 128, 0, 0, 32768, 131072, 4, 64, smem);
    } else {
        dev_tile(t - 512, hb, f1w, f1b, 0, 0, 0, 0, 0, 0, f1,
                 256, 128, 1, 0, 0, 0, 4, 64, smem);
    }
}

// ---- L8: {MFMA pair decoder, single-pass, spill-free} + {feature f2/f3} ----
__global__ void k_decf(const float* hi, const float* hj, const float* e1b,
                       const unsigned short* bfr_g, const float* e2b,
                       const float* e3w, const float* e3b,
                       const float* f1, const float* f2w, const float* f2b_,
                       const float* f3w, const float* f3b,
                       float* lg, float* out) {
    __shared__ float smem[4608];
    int tid = threadIdx.x;
    int blk = blockIdx.x;
    if (blk < 1024) {
        float* red = smem;                           // [256][17] = 4352
        float* pre_sh = smem + 4352;                 // 128
        int lane = tid & 63, wv = tid >> 6;
        int col = lane & 15, quad = lane >> 4;
        int bi = blk, b = bi >> 8;
        if (tid < 128) pre_sh[tid] = hi[bi * 128 + tid] + e1b[tid];
        __syncthreads();
        float e2bv[4], e3wv[4];
        for (int nt = 0; nt < 4; nt++) {
            e2bv[nt] = e2b[nt * 16 + col];
            e3wv[nt] = e3w[nt * 16 + col];
        }
        const float* hjb = hj + b * 32768;
        #pragma unroll 1
        for (int ms = 0; ms < 4; ms++) {
            v4f acc[4];
            for (int nt = 0; nt < 4; nt++) {
                v4f z = {0.f, 0.f, 0.f, 0.f};
                acc[nt] = z;
            }
            int j = wv * 64 + ms * 16 + col;
            const float* rowp = hjb + j * 128 + quad * 8;
            #pragma unroll 1
            for (int kc = 0; kc < 4; kc++) {
                const float* pp = pre_sh + kc * 32 + quad * 8;
                const float* hp = rowp + kc * 32;
                v8s af;
                #pragma unroll
                for (int t = 0; t < 8; t++) {
                    float p = pp[t] + hp[t];
                    p = (p > 0.f) ? p : 0.f;
                    af[t] = (short)f2bs(p);
                }
                #pragma unroll
                for (int nt = 0; nt < 4; nt++) {
                    v8s bf = *(const v8s*)&bfr_g[(((nt * 4 + kc) * 64) + lane) * 8];
                    acc[nt] = __builtin_amdgcn_mfma_f32_16x16x32_bf16(
                        af, bf, acc[nt], 0, 0, 0);
                }
            }
            #pragma unroll
            for (int r = 0; r < 4; r++) {
                float s = 0.f;
                #pragma unroll
                for (int nt = 0; nt < 4; nt++) {
                    float v = acc[nt][r] + e2bv[nt];
                    if (v > 0.f) s += v * e3wv[nt];
                }
                red[(wv * 64 + ms * 16 + quad * 4 + r) * 17 + col] = s;
            }
        }
        __syncthreads();
        float s = e3b[0];
        for (int c = 0; c < 16; c++) s += red[tid * 17 + c];
        lg[bi * 256 + tid] = s;
    } else {
        float* f2row = smem;                         // 512 floats
        int r0 = (blk - 1024) * 4;
        for (int p = 0; p < 2; p++) {
            int idx = tid + p * 256;
            int r = r0 + (idx >> 7), n = idx & 127;
            float s = f2b_[n];
            const float* f1r = f1 + (long)r * 128;
            for (int k = 0; k < 128; k++) s += f1r[k] * f2w[k * 128 + n];
            if (s < 0.f) s = 0.f;
            f2row[idx] = s;
        }
        __syncthreads();
        if (tid < 24) {
            int r = tid / 6, c = tid % 6;
            float s = f3b[c];
            const float* fr = f2row + r * 128;
            for (int k = 0; k < 128; k++) s += fr[k] * f3w[k * 6 + c];
            out[262144 + (r0 + r) * 6 + c] = s;
        }
    }
}

// ---- L9: tiled symmetrize + sigmoid (32x32 tile pairs, LDS transpose) ----
__global__ void k_symsig(const float* lg, float* out) {
    __shared__ float Ta[32 * 33];
    __shared__ float Tb[32 * 33];
    int tid = threadIdx.x;
    int b = blockIdx.x / 36;
    int t = blockIdx.x % 36;
    int ti = 0, rem = t;
    while (rem >= 8 - ti) { rem -= 8 - ti; ti++; }
    int tj = ti + rem;
    int i0 = ti * 32, j0 = tj * 32;
    const float* lgb = lg + b * 65536;
    for (int p = 0; p < 4; p++) {
        int idx = p * 256 + tid;
        int r = idx >> 5, c = idx & 31;
        Ta[r * 33 + c] = lgb[(i0 + r) * 256 + j0 + c];
        Tb[r * 33 + c] = lgb[(j0 + r) * 256 + i0 + c];
    }
    __syncthreads();
    float* ob = out + b * 65536;
    for (int p = 0; p < 4; p++) {
        int idx = p * 256 + tid;
        int r = idx >> 5, c = idx & 31;
        float v1 = 0.5f * (Ta[r * 33 + c] + Tb[c * 33 + r]);
        ob[(i0 + r) * 256 + j0 + c] = 1.f / (1.f + expf(-v1));
        float v2 = 0.5f * (Tb[r * 33 + c] + Ta[c * 33 + r]);
        ob[(j0 + r) * 256 + i0 + c] = 1.f / (1.f + expf(-v2));
    }
}

extern "C" void kernel_launch(void* const* d_in, const int* in_sizes, int n_in,
                              void* d_out, int out_size, void* d_ws, size_t ws_size,
                              hipStream_t stream) {
    const float* x   = (const float*)d_in[0];
    const float* adj = (const float*)d_in[1];
    const float* W1  = (const float*)d_in[2];
    const float* b1  = (const float*)d_in[3];
    const float* W2  = (const float*)d_in[4];
    const float* b2  = (const float*)d_in[5];
    const float* W3  = (const float*)d_in[6];
    const float* b3  = (const float*)d_in[7];
    const float* g1  = (const float*)d_in[8];
    const float* be1 = (const float*)d_in[9];
    const float* g2  = (const float*)d_in[10];
    const float* be2 = (const float*)d_in[11];
    const float* e1w = (const float*)d_in[12];
    const float* e1b = (const float*)d_in[13];
    const float* e2w = (const float*)d_in[14];
    const float* e2b = (const float*)d_in[15];
    const float* e3w = (const float*)d_in[16];
    const float* e3b = (const float*)d_in[17];
    const float* f1w = (const float*)d_in[18];
    const float* f1b = (const float*)d_in[19];
    const float* f2w = (const float*)d_in[20];
    const float* f2b_ = (const float*)d_in[21];
    const float* f3w = (const float*)d_in[22];
    const float* f3b = (const float*)d_in[23];

    float* out = (float*)d_out;

    if (ws_size < (size_t)1600000 * 4) {
        hipMemsetAsync(d_out, 0x60, 4096, stream);   // diagnostic
        return;
    }
    float* ws = (float*)d_ws;
    float* st1 = ws;                        // 256 (zeroed in k_pre)
    float* st2 = ws + 256;                  // 256 (zeroed in k_pre)
    float* dg  = ws + 512;                  // 1024
    unsigned short* bfr_g = (unsigned short*)(ws + 1536);   // 8192 us
    float* An  = ws + 5632;                 // 262144 (materialized by L2)
    float* buf = An + 262144;
    float* hb  = buf + 262144;
    float* lg  = hb + 262144;
    float* h1  = lg + 262144;               // 131072 (later reused as f1)
    float* h2  = h1 + 131072;
    float* hi  = h2 + 131072;
    float* hj  = hi + 131072;               // contiguous after hi (batch-2)

    // L0: x@W1 + degree + e2w swizzle + zero BN accumulators
    k_pre<<<769, 256, 0, stream>>>(x, W1, adj, e2w, buf, dg, bfr_g, st1);
    // L2: h1 = norm(adj)@buf + b1 (+stats->st1); An materialized as byproduct
    k_tgemm<<<256, 256, 0, stream>>>(adj, buf, b1, dg, An, 0, 0, 0, st1, h1,
                                     256, 128, 0, 65536, 32768, 32768, 4, 16);
    // L3: buf = BN(h1)@W2
    k_tgemm<<<256, 256, 0, stream>>>(h1, W2, 0, 0, 0, st1, g1, be1, 0, buf,
                                     128, 128, 0, 0, 0, 0, 4, 64);
    // L4: h2 = An@buf + b2 (+stats -> st2)
    k_tgemm<<<256, 256, 0, stream>>>(An, buf, b2, 0, 0, 0, 0, 0, st2, h2,
                                     256, 128, 0, 65536, 32768, 32768, 4, 16);
    // L5: buf = BN(h2)@W3
    k_tgemm<<<512, 256, 0, stream>>>(h2, W3, 0, 0, 0, st2, g2, be2, 0, buf,
                                     128, 256, 0, 0, 0, 0, 8, 64);
    // L6: hb = relu(An@buf + b3)
    k_tgemm<<<512, 256, 0, stream>>>(An, buf, b3, 0, 0, 0, 0, 0, 0, hb,
                                     256, 256, 1, 65536, 65536, 65536, 8, 16);
    // L7: hi/hj (batch-2) + f1 -> h1
    k_g67<<<768, 256, 0, stream>>>(hb, e1w, hi, f1w, f1b, h1);
    // L8: decoder + feature f2/f3
    k_decf<<<1280, 256, 0, stream>>>(hi, hj, e1b, bfr_g, e2b, e3w, e3b,
                                     h1, f2w, f2b_, f3w, f3b, lg, out);
    // L9: tiled symmetrize + sigmoid
    k_symsig<<<144, 256, 0, stream>>>(lg, out);
}